// Round 1
// baseline (715.539 us; speedup 1.0000x reference)
//
#include <hip/hip_runtime.h>
#include <math.h>

// ---------------------------------------------------------------------------
// Transformer encoder block, MI355X gfx950.
// Round 0: correctness-first full implementation.
//   - bf16 MFMA (16x16x32) GEMMs, m97-style 128x128 tile, global_load_lds w=16
//   - flash attention, causal, online softmax, 64 q-rows per block
//   - ws layout (~120 MB): xnB(16M) | bigB(64M: QKV then H) | oB(16M) |
//     WqkvB(6M) | WoB(2M) | W1B(8M) | W2B(8M) | bqkv(12K)
//   - x1 (post-attention residual) lives in d_out (fully rewritten each call)
// ---------------------------------------------------------------------------

typedef unsigned short u16;
typedef __attribute__((ext_vector_type(8))) short bf16x8;   // 8 bf16 = 4 VGPRs
typedef __attribute__((ext_vector_type(4))) float f32x4;

#define T_TOK 8192      // 4 * 2048 tokens
#define DM    1024      // model dim
#define SEQ   2048
#define NH    16
#define HD    64        // head dim

__device__ __forceinline__ u16 f2bf(float f) {
  union { float f; unsigned int u; } c; c.f = f;
  unsigned int u = c.u + 0x7fffu + ((c.u >> 16) & 1u);   // RNE
  return (u16)(u >> 16);
}

__device__ __forceinline__ void gload16(const void* gp, void* lp) {
  __builtin_amdgcn_global_load_lds(
      (const __attribute__((address_space(1))) void*)gp,
      (__attribute__((address_space(3))) void*)lp, 16, 0, 0);
}

// ---------------------------------------------------------------------------
// elementwise casts / bias concat
// ---------------------------------------------------------------------------
__global__ __launch_bounds__(256) void cast_f2b(const float* __restrict__ in,
                                                u16* __restrict__ out, int n) {
  int i = blockIdx.x * 256 + threadIdx.x;
  int stride = gridDim.x * 256;
  for (; i < n; i += stride) out[i] = f2bf(in[i]);
}

__global__ __launch_bounds__(256) void concat_bias(const float* __restrict__ q,
    const float* __restrict__ k, const float* __restrict__ v, float* __restrict__ out) {
  int i = blockIdx.x * 256 + threadIdx.x;          // 0..3071
  float val = (i < 1024) ? q[i] : (i < 2048) ? k[i - 1024] : v[i - 2048];
  out[i] = val;
}

// ---------------------------------------------------------------------------
// LayerNorm: unbiased var (ddof=1), eps added AFTER sqrt. fp32 in -> bf16 out
// ---------------------------------------------------------------------------
__global__ __launch_bounds__(256) void ln_kernel(const float* __restrict__ x,
    const float* __restrict__ g, const float* __restrict__ b, u16* __restrict__ out) {
  __shared__ float red[4];
  const int tid = threadIdx.x, l = tid & 63, w = tid >> 6;
  const size_t row = blockIdx.x;
  float4 v = reinterpret_cast<const float4*>(x + row * DM)[tid];
  float s = v.x + v.y + v.z + v.w;
#pragma unroll
  for (int off = 1; off < 64; off <<= 1) s += __shfl_xor(s, off, 64);
  if (l == 0) red[w] = s;
  __syncthreads();
  float mu = (red[0] + red[1] + red[2] + red[3]) * (1.0f / 1024.0f);
  float dx = v.x - mu, dy = v.y - mu, dz = v.z - mu, dw = v.w - mu;
  float ss = dx * dx + dy * dy + dz * dz + dw * dw;
#pragma unroll
  for (int off = 1; off < 64; off <<= 1) ss += __shfl_xor(ss, off, 64);
  __syncthreads();                       // guard red[] reuse
  if (l == 0) red[w] = ss;
  __syncthreads();
  float var = (red[0] + red[1] + red[2] + red[3]) * (1.0f / 1023.0f);
  float inv = 1.0f / (sqrtf(var) + 1e-8f);
  const int c = tid * 4;
  u16* o = out + row * DM + c;
  o[0] = f2bf(dx * inv * g[c + 0] + b[c + 0]);
  o[1] = f2bf(dy * inv * g[c + 1] + b[c + 1]);
  o[2] = f2bf(dz * inv * g[c + 2] + b[c + 2]);
  o[3] = f2bf(dw * inv * g[c + 3] + b[c + 3]);
}

// ---------------------------------------------------------------------------
// GEMM: C[M,N] = A[M,K](bf16) @ Bw[N,K](bf16)^T + bias (+res) (+gelu)
// EPI 0: bf16 out (bias)          -- QKV, |  EPI 1: f32 out (bias+res)
// EPI 2: bf16 out (bias+gelu)
// 128x128 block tile, BK=32, 4 waves, each wave 64x64 via 4x4 16x16x32 MFMAs
// ---------------------------------------------------------------------------
template <int EPI>
__global__ __launch_bounds__(256) void gemm_bt(const u16* __restrict__ A,
    const u16* __restrict__ Bw, const float* __restrict__ bias,
    const float* res, void* Cout, int M, int N, int K) {
  __shared__ __align__(16) u16 ldsA[128 * 32];
  __shared__ __align__(16) u16 ldsB[128 * 32];
  const int tid = threadIdx.x;
  const int l = tid & 63;
  const int w = tid >> 6;
  const int m0 = blockIdx.y * 128, n0 = blockIdx.x * 128;
  const int wr = (w >> 1) * 64, wc = (w & 1) * 64;
  const int lr = l & 15, lk = (l >> 4) * 8, lg = l >> 4;

  f32x4 acc[4][4];
#pragma unroll
  for (int i = 0; i < 4; ++i)
#pragma unroll
    for (int j = 0; j < 4; ++j) acc[i][j] = f32x4{0.f, 0.f, 0.f, 0.f};

  const int ea0 = tid * 8, ea1 = tid * 8 + 2048;   // element offsets in tile
  const int ra0 = ea0 >> 5, ca0 = ea0 & 31;
  const int ra1 = ea1 >> 5, ca1 = ea1 & 31;

  for (int k0 = 0; k0 < K; k0 += 32) {
    gload16(A + (size_t)(m0 + ra0) * K + k0 + ca0, &ldsA[ea0]);
    gload16(A + (size_t)(m0 + ra1) * K + k0 + ca1, &ldsA[ea1]);
    gload16(Bw + (size_t)(n0 + ra0) * K + k0 + ca0, &ldsB[ea0]);
    gload16(Bw + (size_t)(n0 + ra1) * K + k0 + ca1, &ldsB[ea1]);
    __syncthreads();   // drains vmcnt for global_load_lds
    bf16x8 av[4], bv[4];
#pragma unroll
    for (int i = 0; i < 4; ++i) {
      av[i] = *(const bf16x8*)&ldsA[(wr + i * 16 + lr) * 32 + lk];
      bv[i] = *(const bf16x8*)&ldsB[(wc + i * 16 + lr) * 32 + lk];
    }
#pragma unroll
    for (int mi = 0; mi < 4; ++mi)
#pragma unroll
      for (int ni = 0; ni < 4; ++ni)
        acc[mi][ni] = __builtin_amdgcn_mfma_f32_16x16x32_bf16(
            av[mi], bv[ni], acc[mi][ni], 0, 0, 0);
    __syncthreads();
  }

#pragma unroll
  for (int ni = 0; ni < 4; ++ni) {
    const int c = n0 + wc + ni * 16 + lr;
    const float bs = bias[c];
#pragma unroll
    for (int mi = 0; mi < 4; ++mi) {
#pragma unroll
      for (int j = 0; j < 4; ++j) {
        const int r = m0 + wr + mi * 16 + lg * 4 + j;
        const size_t idx = (size_t)r * N + c;
        float v = acc[mi][ni][j] + bs;
        if constexpr (EPI == 0) {
          ((u16*)Cout)[idx] = f2bf(v);
        } else if constexpr (EPI == 1) {
          ((float*)Cout)[idx] = v + res[idx];
        } else {
          float gv = 0.5f * v * (1.0f + erff(v * 0.70710678118654752f));
          ((u16*)Cout)[idx] = f2bf(gv);
        }
      }
    }
  }
}

// ---------------------------------------------------------------------------
// Flash attention (causal). QKV bf16 [T,3072] (Q|K|V each [T,H,64]).
// Block: one (b,h,qtile of 64). 4 waves, each wave 16 q-rows.
// K staged [64][72] padded; V staged transposed [64d][72k]; P via per-wave LDS.
// ---------------------------------------------------------------------------
__global__ __launch_bounds__(256) void attn_kernel(const u16* __restrict__ qkv,
                                                   u16* __restrict__ obuf) {
  __shared__ __align__(16) u16 ldsK[64 * 72];
  __shared__ __align__(16) u16 ldsV[64 * 72];       // transposed: [d][k]
  __shared__ __align__(16) u16 ldsP[4][16 * 72];    // per-wave P tile
  const int tid = threadIdx.x, l = tid & 63, w = tid >> 6;
  const int qt = blockIdx.x, bh = blockIdx.y, b = bh >> 4, h = bh & 15;
  const int lr = l & 15, lg = l >> 4;
  const u16* base = qkv + (size_t)b * SEQ * 3072 + h * 64;

  // Q fragments (A operand rows = l&15)
  const int qrow = qt * 64 + w * 16 + lr;
  bf16x8 qf[2];
  qf[0] = *(const bf16x8*)(base + (size_t)qrow * 3072 + lg * 8);
  qf[1] = *(const bf16x8*)(base + (size_t)qrow * 3072 + 32 + lg * 8);

  f32x4 o[4];
#pragma unroll
  for (int i = 0; i < 4; ++i) o[i] = f32x4{0.f, 0.f, 0.f, 0.f};
  float m_[4] = {-1e30f, -1e30f, -1e30f, -1e30f};
  float ls[4] = {0.f, 0.f, 0.f, 0.f};

  const int e0 = tid * 8, e1 = tid * 8 + 2048;
  const int k0r = e0 >> 6, k0c = e0 & 63;   // tile row (key), col (d)
  const int k1r = e1 >> 6, k1c = e1 & 63;
  const int nt = qt + 1;

  for (int kt = 0; kt < nt; ++kt) {
    const u16* Kp = base + 1024 + (size_t)kt * 64 * 3072;
    const u16* Vp = base + 2048 + (size_t)kt * 64 * 3072;
    bf16x8 kv0 = *(const bf16x8*)(Kp + (size_t)k0r * 3072 + k0c);
    bf16x8 kv1 = *(const bf16x8*)(Kp + (size_t)k1r * 3072 + k1c);
    bf16x8 vv0 = *(const bf16x8*)(Vp + (size_t)k0r * 3072 + k0c);
    bf16x8 vv1 = *(const bf16x8*)(Vp + (size_t)k1r * 3072 + k1c);
    __syncthreads();   // previous iteration's LDS reads complete
    *(bf16x8*)&ldsK[k0r * 72 + k0c] = kv0;
    *(bf16x8*)&ldsK[k1r * 72 + k1c] = kv1;
#pragma unroll
    for (int i = 0; i < 8; ++i) ldsV[(k0c + i) * 72 + k0r] = (u16)vv0[i];
#pragma unroll
    for (int i = 0; i < 8; ++i) ldsV[(k1c + i) * 72 + k1r] = (u16)vv1[i];
    __syncthreads();

    // S = Q K^T  (per wave: 16q x 64k)
    f32x4 sc[4];
#pragma unroll
    for (int i = 0; i < 4; ++i) sc[i] = f32x4{0.f, 0.f, 0.f, 0.f};
#pragma unroll
    for (int ks = 0; ks < 2; ++ks)
#pragma unroll
      for (int ni = 0; ni < 4; ++ni) {
        bf16x8 kf = *(const bf16x8*)&ldsK[(ni * 16 + lr) * 72 + ks * 32 + lg * 8];
        sc[ni] = __builtin_amdgcn_mfma_f32_16x16x32_bf16(qf[ks], kf, sc[ni], 0, 0, 0);
      }

    // scale + causal mask (D layout: row=lg*4+j, col=lr)
    const int keyb = kt * 64;
    const int qb = qt * 64 + w * 16 + lg * 4;
#pragma unroll
    for (int ni = 0; ni < 4; ++ni)
#pragma unroll
      for (int j = 0; j < 4; ++j) {
        float s = sc[ni][j] * 0.125f;
        if (keyb + ni * 16 + lr > qb + j) s = -1e30f;
        sc[ni][j] = s;
      }

    // online softmax, rows j=0..3 of this 16-lane group
#pragma unroll
    for (int j = 0; j < 4; ++j) {
      float v = fmaxf(fmaxf(sc[0][j], sc[1][j]), fmaxf(sc[2][j], sc[3][j]));
      v = fmaxf(v, __shfl_xor(v, 1, 16));
      v = fmaxf(v, __shfl_xor(v, 2, 16));
      v = fmaxf(v, __shfl_xor(v, 4, 16));
      v = fmaxf(v, __shfl_xor(v, 8, 16));
      float newm = fmaxf(m_[j], v);
      float alpha = __expf(m_[j] - newm);
      float psum = 0.f;
#pragma unroll
      for (int ni = 0; ni < 4; ++ni) {
        float p = __expf(sc[ni][j] - newm);
        psum += p;
        ldsP[w][(lg * 4 + j) * 72 + ni * 16 + lr] = f2bf(p);
      }
      psum += __shfl_xor(psum, 1, 16);
      psum += __shfl_xor(psum, 2, 16);
      psum += __shfl_xor(psum, 4, 16);
      psum += __shfl_xor(psum, 8, 16);
      ls[j] = ls[j] * alpha + psum;
      m_[j] = newm;
#pragma unroll
      for (int nd = 0; nd < 4; ++nd) o[nd][j] *= alpha;
    }

    // O += P V   (A=P from LDS, B=V from transposed LDS)
#pragma unroll
    for (int ks = 0; ks < 2; ++ks) {
      bf16x8 pf = *(const bf16x8*)&ldsP[w][lr * 72 + ks * 32 + lg * 8];
#pragma unroll
      for (int nd = 0; nd < 4; ++nd) {
        bf16x8 vf = *(const bf16x8*)&ldsV[(nd * 16 + lr) * 72 + ks * 32 + lg * 8];
        o[nd] = __builtin_amdgcn_mfma_f32_16x16x32_bf16(pf, vf, o[nd], 0, 0, 0);
      }
    }
  }

#pragma unroll
  for (int j = 0; j < 4; ++j) {
    float inv = 1.0f / ls[j];
    const size_t trow = (size_t)b * SEQ + qt * 64 + w * 16 + lg * 4 + j;
#pragma unroll
    for (int nd = 0; nd < 4; ++nd)
      obuf[trow * DM + h * 64 + nd * 16 + lr] = f2bf(o[nd][j] * inv);
  }
}

// ---------------------------------------------------------------------------
extern "C" void kernel_launch(void* const* d_in, const int* in_sizes, int n_in,
                              void* d_out, int out_size, void* d_ws, size_t ws_size,
                              hipStream_t stream) {
  const float* x   = (const float*)d_in[0];
  const float* Wq  = (const float*)d_in[1];
  const float* bq  = (const float*)d_in[2];
  const float* Wk  = (const float*)d_in[3];
  const float* bk  = (const float*)d_in[4];
  const float* Wv  = (const float*)d_in[5];
  const float* bv  = (const float*)d_in[6];
  const float* Wo  = (const float*)d_in[7];
  const float* bo  = (const float*)d_in[8];
  const float* g1  = (const float*)d_in[9];
  const float* be1 = (const float*)d_in[10];
  const float* g2  = (const float*)d_in[11];
  const float* be2 = (const float*)d_in[12];
  const float* W1  = (const float*)d_in[13];
  const float* bf1 = (const float*)d_in[14];
  const float* W2  = (const float*)d_in[15];
  const float* bf2 = (const float*)d_in[16];
  float* out = (float*)d_out;   // also hosts x1 (post-attn residual)

  char* ws = (char*)d_ws;
  size_t off = 0;
  auto alloc = [&](size_t bytes) {
    char* p = ws + off;
    off += (bytes + 255) & ~(size_t)255;
    return p;
  };
  u16*   xnB   = (u16*)alloc((size_t)T_TOK * DM * 2);        // 16 MB (xn, later xn2)
  u16*   bigB  = (u16*)alloc((size_t)T_TOK * 4096 * 2);      // 64 MB (QKV, later H)
  u16*   oB    = (u16*)alloc((size_t)T_TOK * DM * 2);        // 16 MB attn out
  u16*   WqkvB = (u16*)alloc((size_t)3072 * 1024 * 2);       // 6 MB
  u16*   WoB   = (u16*)alloc((size_t)1024 * 1024 * 2);       // 2 MB
  u16*   W1B   = (u16*)alloc((size_t)4096 * 1024 * 2);       // 8 MB
  u16*   W2B   = (u16*)alloc((size_t)1024 * 4096 * 2);       // 8 MB
  float* bqkv  = (float*)alloc(3072 * 4);

  // weight casts (bf16)
  cast_f2b<<<1024, 256, 0, stream>>>(Wq, WqkvB,                1024 * 1024);
  cast_f2b<<<1024, 256, 0, stream>>>(Wk, WqkvB + 1024 * 1024,  1024 * 1024);
  cast_f2b<<<1024, 256, 0, stream>>>(Wv, WqkvB + 2048 * 1024,  1024 * 1024);
  cast_f2b<<<1024, 256, 0, stream>>>(Wo, WoB, 1024 * 1024);
  cast_f2b<<<2048, 256, 0, stream>>>(W1, W1B, 4 * 1024 * 1024);
  cast_f2b<<<2048, 256, 0, stream>>>(W2, W2B, 4 * 1024 * 1024);
  concat_bias<<<12, 256, 0, stream>>>(bq, bk, bv, bqkv);

  // MHA sublayer
  ln_kernel<<<T_TOK, 256, 0, stream>>>(x, g1, be1, xnB);
  gemm_bt<0><<<dim3(24, 64), 256, 0, stream>>>(xnB, WqkvB, bqkv, nullptr,
                                               bigB, T_TOK, 3072, 1024);
  attn_kernel<<<dim3(32, 64), 256, 0, stream>>>(bigB, oB);
  gemm_bt<1><<<dim3(8, 64), 256, 0, stream>>>(oB, WoB, bo, x,
                                              out, T_TOK, 1024, 1024);   // x1 -> d_out

  // FFN sublayer
  ln_kernel<<<T_TOK, 256, 0, stream>>>(out, g2, be2, xnB);
  gemm_bt<2><<<dim3(32, 64), 256, 0, stream>>>(xnB, W1B, bf1, nullptr,
                                               bigB, T_TOK, 4096, 1024);
  gemm_bt<1><<<dim3(8, 64), 256, 0, stream>>>(bigB, W2B, bf2, out,
                                              out, T_TOK, 1024, 4096);
}

// Round 2
// 504.918 us; speedup vs baseline: 1.4171x; 1.4171x over previous
//
#include <hip/hip_runtime.h>
#include <math.h>

// ---------------------------------------------------------------------------
// Transformer encoder block, MI355X gfx950.  Round 2: attention rewrite.
//   - swapped QK^T (S^T = mfma(K,Q)) -> lane-local softmax rows, packed P
//   - V pre-transposed by QKV-GEMM epilogue -> VT[b][h][d][s]
//   - K/VT staged via global_load_lds w=16 + XOR swizzle (pre-swizzled source)
//   - QBLK=256 (8 waves x 32q), KBLK=64, paired q-tiles for load balance
// ---------------------------------------------------------------------------

typedef unsigned short u16;
typedef unsigned int u32;
typedef __attribute__((ext_vector_type(8))) short bf16x8;   // 8 bf16 = 4 VGPRs
typedef __attribute__((ext_vector_type(4))) float f32x4;

#define T_TOK 8192      // 4 * 2048 tokens
#define DM    1024      // model dim
#define SEQ   2048
#define NH    16
#define HD    64        // head dim

__device__ __forceinline__ u16 f2bf(float f) {
  union { float f; unsigned int u; } c; c.f = f;
  unsigned int u = c.u + 0x7fffu + ((c.u >> 16) & 1u);   // RNE
  return (u16)(u >> 16);
}

__device__ __forceinline__ u32 pk2(float a, float b) {
  return (u32)f2bf(a) | ((u32)f2bf(b) << 16);
}

__device__ __forceinline__ float bf2f(short s) {
  union { float f; unsigned int u; } c; c.u = ((u32)(u16)s) << 16;
  return c.f;
}

__device__ __forceinline__ void gload16(const void* gp, void* lp) {
  __builtin_amdgcn_global_load_lds(
      (const __attribute__((address_space(1))) void*)gp,
      (__attribute__((address_space(3))) void*)lp, 16, 0, 0);
}

// ---------------------------------------------------------------------------
// elementwise casts / bias concat
// ---------------------------------------------------------------------------
__global__ __launch_bounds__(256) void cast_f2b(const float* __restrict__ in,
                                                u16* __restrict__ out, int n) {
  int i = blockIdx.x * 256 + threadIdx.x;
  int stride = gridDim.x * 256;
  for (; i < n; i += stride) out[i] = f2bf(in[i]);
}

__global__ __launch_bounds__(256) void concat_bias(const float* __restrict__ q,
    const float* __restrict__ k, const float* __restrict__ v, float* __restrict__ out) {
  int i = blockIdx.x * 256 + threadIdx.x;          // 0..3071
  float val = (i < 1024) ? q[i] : (i < 2048) ? k[i - 1024] : v[i - 2048];
  out[i] = val;
}

// ---------------------------------------------------------------------------
// LayerNorm: unbiased var (ddof=1), eps added AFTER sqrt. fp32 in -> bf16 out
// ---------------------------------------------------------------------------
__global__ __launch_bounds__(256) void ln_kernel(const float* __restrict__ x,
    const float* __restrict__ g, const float* __restrict__ b, u16* __restrict__ out) {
  __shared__ float red[4];
  const int tid = threadIdx.x, l = tid & 63, w = tid >> 6;
  const size_t row = blockIdx.x;
  float4 v = reinterpret_cast<const float4*>(x + row * DM)[tid];
  float s = v.x + v.y + v.z + v.w;
#pragma unroll
  for (int off = 1; off < 64; off <<= 1) s += __shfl_xor(s, off, 64);
  if (l == 0) red[w] = s;
  __syncthreads();
  float mu = (red[0] + red[1] + red[2] + red[3]) * (1.0f / 1024.0f);
  float dx = v.x - mu, dy = v.y - mu, dz = v.z - mu, dw = v.w - mu;
  float ss = dx * dx + dy * dy + dz * dz + dw * dw;
#pragma unroll
  for (int off = 1; off < 64; off <<= 1) ss += __shfl_xor(ss, off, 64);
  __syncthreads();                       // guard red[] reuse
  if (l == 0) red[w] = ss;
  __syncthreads();
  float var = (red[0] + red[1] + red[2] + red[3]) * (1.0f / 1023.0f);
  float inv = 1.0f / (sqrtf(var) + 1e-8f);
  const int c = tid * 4;
  u16* o = out + row * DM + c;
  o[0] = f2bf(dx * inv * g[c + 0] + b[c + 0]);
  o[1] = f2bf(dy * inv * g[c + 1] + b[c + 1]);
  o[2] = f2bf(dz * inv * g[c + 2] + b[c + 2]);
  o[3] = f2bf(dw * inv * g[c + 3] + b[c + 3]);
}

// ---------------------------------------------------------------------------
// GEMM: C[M,N] = A[M,K](bf16) @ Bw[N,K](bf16)^T + bias (+res) (+gelu)
// EPI 0: QKV special -- Q,K cols (<2048) -> bf16 qk buffer (row stride 2048),
//        V cols (>=2048) -> transposed bf16 into aux = VT[b][h][64][2048]
// EPI 1: f32 out (bias + res)
// EPI 2: bf16 out (bias + gelu)
// 128x128 block tile, BK=32, 4 waves, each wave 64x64 via 4x4 16x16x32 MFMAs
// ---------------------------------------------------------------------------
template <int EPI>
__global__ __launch_bounds__(256) void gemm_bt(const u16* __restrict__ A,
    const u16* __restrict__ Bw, const float* __restrict__ bias,
    const float* res, void* Cout, void* aux, int M, int N, int K) {
  __shared__ __align__(16) u16 ldsA[128 * 32];
  __shared__ __align__(16) u16 ldsB[128 * 32];
  const int tid = threadIdx.x;
  const int l = tid & 63;
  const int w = tid >> 6;
  const int m0 = blockIdx.y * 128, n0 = blockIdx.x * 128;
  const int wr = (w >> 1) * 64, wc = (w & 1) * 64;
  const int lr = l & 15, lk = (l >> 4) * 8, lg = l >> 4;

  f32x4 acc[4][4];
#pragma unroll
  for (int i = 0; i < 4; ++i)
#pragma unroll
    for (int j = 0; j < 4; ++j) acc[i][j] = f32x4{0.f, 0.f, 0.f, 0.f};

  const int ea0 = tid * 8, ea1 = tid * 8 + 2048;   // element offsets in tile
  const int ra0 = ea0 >> 5, ca0 = ea0 & 31;
  const int ra1 = ea1 >> 5, ca1 = ea1 & 31;

  for (int k0 = 0; k0 < K; k0 += 32) {
    gload16(A + (size_t)(m0 + ra0) * K + k0 + ca0, &ldsA[ea0]);
    gload16(A + (size_t)(m0 + ra1) * K + k0 + ca1, &ldsA[ea1]);
    gload16(Bw + (size_t)(n0 + ra0) * K + k0 + ca0, &ldsB[ea0]);
    gload16(Bw + (size_t)(n0 + ra1) * K + k0 + ca1, &ldsB[ea1]);
    __syncthreads();   // drains vmcnt for global_load_lds
    bf16x8 av[4], bv[4];
#pragma unroll
    for (int i = 0; i < 4; ++i) {
      av[i] = *(const bf16x8*)&ldsA[(wr + i * 16 + lr) * 32 + lk];
      bv[i] = *(const bf16x8*)&ldsB[(wc + i * 16 + lr) * 32 + lk];
    }
#pragma unroll
    for (int mi = 0; mi < 4; ++mi)
#pragma unroll
      for (int ni = 0; ni < 4; ++ni)
        acc[mi][ni] = __builtin_amdgcn_mfma_f32_16x16x32_bf16(
            av[mi], bv[ni], acc[mi][ni], 0, 0, 0);
    __syncthreads();
  }

#pragma unroll
  for (int ni = 0; ni < 4; ++ni) {
    const int c = n0 + wc + ni * 16 + lr;
    const float bs = bias[c];
#pragma unroll
    for (int mi = 0; mi < 4; ++mi) {
#pragma unroll
      for (int j = 0; j < 4; ++j) {
        const int r = m0 + wr + mi * 16 + lg * 4 + j;
        float v = acc[mi][ni][j] + bs;
        if constexpr (EPI == 0) {
          if (n0 >= 2048) {             // V tile -> transposed write (uniform)
            const int hd = c - 2048, hh = hd >> 6, d = hd & 63;
            const int bb = r >> 11, s = r & 2047;
            ((u16*)aux)[(((size_t)(bb * 16 + hh) * 64 + d) << 11) + s] = f2bf(v);
          } else {                      // Q,K -> [T][2048]
            ((u16*)Cout)[(size_t)r * 2048 + c] = f2bf(v);
          }
        } else if constexpr (EPI == 1) {
          const size_t idx = (size_t)r * N + c;
          ((float*)Cout)[idx] = v + res[idx];
        } else {
          const size_t idx = (size_t)r * N + c;
          float gv = 0.5f * v * (1.0f + erff(v * 0.70710678118654752f));
          ((u16*)Cout)[idx] = f2bf(gv);
        }
      }
    }
  }
}

// ---------------------------------------------------------------------------
// Flash attention (causal), swapped-QK form.
//   qk: [T][2048] bf16 (Q cols 0..1023, K cols 1024..2047), vt: [B*H][64][2048]
//   Block: 512 threads (8 waves), handles q-tile pair (bx, 7-bx) for one (b,h).
//   Per wave: 32 q rows (mi=2 x 16). KBLK=64.
//   K tile [64k][64d] and VT tile [64d][64k] in LDS, XOR-swizzled, staged via
//   global_load_lds from pre-swizzled source addresses.
//   S^T = mfma(A=K, B=Q) -> lane holds 16 scores of ONE q-row (q = lane&15);
//   softmax reduce = local tree + shfl_xor(16,32); P packed b64 into [q][k] LDS.
// ---------------------------------------------------------------------------
__global__ __launch_bounds__(512) void attn_kernel(const u16* __restrict__ qk,
    const u16* __restrict__ vt, u16* __restrict__ obuf) {
  __shared__ __align__(16) u16 ldsK[64 * 64];
  __shared__ __align__(16) u16 ldsV[64 * 64];
  __shared__ __align__(16) u16 ldsP[8][2][16 * 72];
  const int tid = threadIdx.x, l = tid & 63, w = tid >> 6;
  const int lr = l & 15, lg = l >> 4;
  const int bx = blockIdx.x;                     // 0..3 (q-tile pair)
  const int bh = blockIdx.y, b = bh >> 4, h = bh & 15;
  const u16* qbase = qk + (size_t)b * SEQ * 2048 + h * 64;
  const u16* kbase = qk + (size_t)b * SEQ * 2048 + 1024 + h * 64;
  const u16* vbase = vt + (size_t)bh * 64 * SEQ;

  // staging geometry: 512 thr x 16B = 8 KB = one full tile per pass
  const int srow = tid >> 3;                     // 0..63
  const int scb  = ((tid & 7) * 16) ^ ((srow & 7) << 4);   // swizzled col bytes
  const int sel  = scb >> 1;                     // element offset in 64-col row

#pragma unroll
  for (int half = 0; half < 2; ++half) {
    const int qt = half ? (7 - bx) : bx;
    const int q0 = qt * 256 + w * 32;            // wave's first q row
    // Q fragments (B operand: lane holds Q[q=lr][d=lg*8+i]), pre-scaled 1/8
    bf16x8 qf[2][2];
#pragma unroll
    for (int mi = 0; mi < 2; ++mi)
#pragma unroll
      for (int ks = 0; ks < 2; ++ks) {
        bf16x8 raw = *(const bf16x8*)(qbase +
            (size_t)(q0 + mi * 16 + lr) * 2048 + ks * 32 + lg * 8);
        bf16x8 sc8;
#pragma unroll
        for (int i = 0; i < 8; ++i) sc8[i] = (short)f2bf(bf2f(raw[i]) * 0.125f);
        qf[mi][ks] = sc8;
      }

    f32x4 o[2][4];
#pragma unroll
    for (int mi = 0; mi < 2; ++mi)
#pragma unroll
      for (int nd = 0; nd < 4; ++nd) o[mi][nd] = f32x4{0.f, 0.f, 0.f, 0.f};
    float m_[2] = {-1e30f, -1e30f}, ls[2] = {0.f, 0.f};

    const int nt = 4 * qt + 4;
    const int qmaxw = q0 + 31;

    for (int kt = 0; kt < nt; ++kt) {
      // ---- stage K and VT tiles (pre-swizzled source, linear LDS dest) ----
      gload16(kbase + (size_t)(kt * 64 + srow) * 2048 + sel, &ldsK[tid * 8]);
      gload16(vbase + (size_t)srow * SEQ + kt * 64 + sel,    &ldsV[tid * 8]);
      __syncthreads();

      if (kt * 64 <= qmaxw) {          // wave has live rows in this k-tile
        // ---- S^T = K . Q^T ----
        f32x4 sc[2][4];
#pragma unroll
        for (int mi = 0; mi < 2; ++mi)
#pragma unroll
          for (int ni = 0; ni < 4; ++ni) sc[mi][ni] = f32x4{0.f, 0.f, 0.f, 0.f};
#pragma unroll
        for (int ks = 0; ks < 2; ++ks)
#pragma unroll
          for (int ni = 0; ni < 4; ++ni) {
            const int r = ni * 16 + lr;
            const int cb = (r << 7) + ((ks * 64 + lg * 16) ^ ((r & 7) << 4));
            bf16x8 kf = *(const bf16x8*)&ldsK[cb >> 1];
            sc[0][ni] = __builtin_amdgcn_mfma_f32_16x16x32_bf16(kf, qf[0][ks], sc[0][ni], 0, 0, 0);
            sc[1][ni] = __builtin_amdgcn_mfma_f32_16x16x32_bf16(kf, qf[1][ks], sc[1][ni], 0, 0, 0);
          }

        // ---- causal mask (only diagonal-band tiles) ----
        if (kt * 64 + 63 > q0) {
#pragma unroll
          for (int mi = 0; mi < 2; ++mi) {
            const int qa = q0 + mi * 16 + lr;
#pragma unroll
            for (int ni = 0; ni < 4; ++ni)
#pragma unroll
              for (int j = 0; j < 4; ++j) {
                const int ka = kt * 64 + ni * 16 + lg * 4 + j;
                if (ka > qa) sc[mi][ni][j] = -1e30f;
              }
          }
        }

        // ---- online softmax (row q = lane&15, 16 scores/lane + 2 shfl) ----
#pragma unroll
        for (int mi = 0; mi < 2; ++mi) {
          float mx = sc[mi][0][0];
#pragma unroll
          for (int ni = 0; ni < 4; ++ni)
#pragma unroll
            for (int j = 0; j < 4; ++j) mx = fmaxf(mx, sc[mi][ni][j]);
          mx = fmaxf(mx, __shfl_xor(mx, 16, 64));
          mx = fmaxf(mx, __shfl_xor(mx, 32, 64));
          const float newm = fmaxf(m_[mi], mx);
          const float alpha = __expf(m_[mi] - newm);
          m_[mi] = newm;
          float ps = 0.f;
#pragma unroll
          for (int ni = 0; ni < 4; ++ni) {
            float p0 = __expf(sc[mi][ni][0] - newm);
            float p1 = __expf(sc[mi][ni][1] - newm);
            float p2 = __expf(sc[mi][ni][2] - newm);
            float p3 = __expf(sc[mi][ni][3] - newm);
            ps += (p0 + p1) + (p2 + p3);
            u32 w0 = pk2(p0, p1), w1 = pk2(p2, p3);
            *(uint2*)&ldsP[w][mi][lr * 72 + ni * 16 + lg * 4] = make_uint2(w0, w1);
          }
          ps += __shfl_xor(ps, 16, 64);
          ps += __shfl_xor(ps, 32, 64);
          ls[mi] = ls[mi] * alpha + ps;
          const float a0 = __shfl(alpha, lg * 4 + 0, 16);
          const float a1 = __shfl(alpha, lg * 4 + 1, 16);
          const float a2 = __shfl(alpha, lg * 4 + 2, 16);
          const float a3 = __shfl(alpha, lg * 4 + 3, 16);
#pragma unroll
          for (int nd = 0; nd < 4; ++nd) {
            o[mi][nd][0] *= a0; o[mi][nd][1] *= a1;
            o[mi][nd][2] *= a2; o[mi][nd][3] *= a3;
          }
        }

        // ---- O += P V ----
#pragma unroll
        for (int ks = 0; ks < 2; ++ks) {
          bf16x8 pf0 = *(const bf16x8*)&ldsP[w][0][lr * 72 + ks * 32 + lg * 8];
          bf16x8 pf1 = *(const bf16x8*)&ldsP[w][1][lr * 72 + ks * 32 + lg * 8];
#pragma unroll
          for (int nd = 0; nd < 4; ++nd) {
            const int r = nd * 16 + lr;
            const int cb = (r << 7) + ((ks * 64 + lg * 16) ^ ((r & 7) << 4));
            bf16x8 vf = *(const bf16x8*)&ldsV[cb >> 1];
            o[0][nd] = __builtin_amdgcn_mfma_f32_16x16x32_bf16(pf0, vf, o[0][nd], 0, 0, 0);
            o[1][nd] = __builtin_amdgcn_mfma_f32_16x16x32_bf16(pf1, vf, o[1][nd], 0, 0, 0);
          }
        }
      }
      __syncthreads();    // before next stage overwrites K/VT
    }

    // ---- epilogue: O / l ----
#pragma unroll
    for (int mi = 0; mi < 2; ++mi) {
      const float i0 = 1.0f / __shfl(ls[mi], lg * 4 + 0, 16);
      const float i1 = 1.0f / __shfl(ls[mi], lg * 4 + 1, 16);
      const float i2 = 1.0f / __shfl(ls[mi], lg * 4 + 2, 16);
      const float i3 = 1.0f / __shfl(ls[mi], lg * 4 + 3, 16);
      const int qrow = q0 + mi * 16 + lg * 4;
#pragma unroll
      for (int nd = 0; nd < 4; ++nd) {
        const int d = nd * 16 + lr;
        u16* op = obuf + (size_t)(b * SEQ + qrow) * DM + h * 64 + d;
        op[0 * DM] = f2bf(o[mi][nd][0] * i0);
        op[1 * DM] = f2bf(o[mi][nd][1] * i1);
        op[2 * DM] = f2bf(o[mi][nd][2] * i2);
        op[3 * DM] = f2bf(o[mi][nd][3] * i3);
      }
    }
  }
}

// ---------------------------------------------------------------------------
extern "C" void kernel_launch(void* const* d_in, const int* in_sizes, int n_in,
                              void* d_out, int out_size, void* d_ws, size_t ws_size,
                              hipStream_t stream) {
  const float* x   = (const float*)d_in[0];
  const float* Wq  = (const float*)d_in[1];
  const float* bq  = (const float*)d_in[2];
  const float* Wk  = (const float*)d_in[3];
  const float* bk  = (const float*)d_in[4];
  const float* Wv  = (const float*)d_in[5];
  const float* bv  = (const float*)d_in[6];
  const float* Wo  = (const float*)d_in[7];
  const float* bo  = (const float*)d_in[8];
  const float* g1  = (const float*)d_in[9];
  const float* be1 = (const float*)d_in[10];
  const float* g2  = (const float*)d_in[11];
  const float* be2 = (const float*)d_in[12];
  const float* W1  = (const float*)d_in[13];
  const float* bf1 = (const float*)d_in[14];
  const float* W2  = (const float*)d_in[15];
  const float* bf2 = (const float*)d_in[16];
  float* out = (float*)d_out;   // also hosts x1 (post-attn residual)

  char* ws = (char*)d_ws;
  size_t off = 0;
  auto alloc = [&](size_t bytes) {
    char* p = ws + off;
    off += (bytes + 255) & ~(size_t)255;
    return p;
  };
  u16* xnB = (u16*)alloc((size_t)T_TOK * DM * 2);     // 16 MB (xn, later xn2)
  // Region D (64 MB): during MHA = qkB(32) | VTg(16) | oB(16); during FFN = H
  u16* D    = (u16*)alloc((size_t)T_TOK * 4096 * 2);  // 64 MB
  u16* qkB  = D;                                      // [T][2048]
  u16* VTg  = D + (size_t)T_TOK * 2048;               // [B*H][64][2048]
  u16* oB   = D + (size_t)T_TOK * 3072;               // [T][1024]
  u16* HB   = D;                                      // [T][4096] (FFN phase)
  u16*   WqkvB = (u16*)alloc((size_t)3072 * 1024 * 2);
  u16*   WoB   = (u16*)alloc((size_t)1024 * 1024 * 2);
  u16*   W1B   = (u16*)alloc((size_t)4096 * 1024 * 2);
  u16*   W2B   = (u16*)alloc((size_t)1024 * 4096 * 2);
  float* bqkv  = (float*)alloc(3072 * 4);

  // weight casts (bf16)
  cast_f2b<<<1024, 256, 0, stream>>>(Wq, WqkvB,                1024 * 1024);
  cast_f2b<<<1024, 256, 0, stream>>>(Wk, WqkvB + 1024 * 1024,  1024 * 1024);
  cast_f2b<<<1024, 256, 0, stream>>>(Wv, WqkvB + 2048 * 1024,  1024 * 1024);
  cast_f2b<<<1024, 256, 0, stream>>>(Wo, WoB, 1024 * 1024);
  cast_f2b<<<2048, 256, 0, stream>>>(W1, W1B, 4 * 1024 * 1024);
  cast_f2b<<<2048, 256, 0, stream>>>(W2, W2B, 4 * 1024 * 1024);
  concat_bias<<<12, 256, 0, stream>>>(bq, bk, bv, bqkv);

  // MHA sublayer
  ln_kernel<<<T_TOK, 256, 0, stream>>>(x, g1, be1, xnB);
  gemm_bt<0><<<dim3(24, 64), 256, 0, stream>>>(xnB, WqkvB, bqkv, nullptr,
                                               qkB, VTg, T_TOK, 3072, 1024);
  attn_kernel<<<dim3(4, 64), 512, 0, stream>>>(qkB, VTg, oB);
  gemm_bt<1><<<dim3(8, 64), 256, 0, stream>>>(oB, WoB, bo, x,
                                              out, nullptr, T_TOK, 1024, 1024);

  // FFN sublayer
  ln_kernel<<<T_TOK, 256, 0, stream>>>(out, g2, be2, xnB);
  gemm_bt<2><<<dim3(32, 64), 256, 0, stream>>>(xnB, W1B, bf1, nullptr,
                                               HB, nullptr, T_TOK, 4096, 1024);
  gemm_bt<1><<<dim3(8, 64), 256, 0, stream>>>(HB, W2B, bf2, out,
                                              out, nullptr, T_TOK, 1024, 4096);
}